// Round 1
// baseline (2904.554 us; speedup 1.0000x reference)
//
#include <hip/hip_runtime.h>

#define R_    16
#define NBAS  30
#define DIN1  128
#define DHID  128
#define DOUT2 64
#define DADR  400

// ---------------- count edges per (dst, relation) bucket ----------------
__global__ __launch_bounds__(256) void count_kernel(const int* __restrict__ dst,
                                                    const int* __restrict__ ety,
                                                    float* __restrict__ cnt, int E) {
    int e = blockIdx.x * blockDim.x + threadIdx.x;
    if (e < E) atomicAdd(&cnt[dst[e] * R_ + ety[e]], 1.0f);
}

// ---------------- w[r,i,o] = sum_b comp[r,b] * basis[b,i,o] ----------------
__global__ __launch_bounds__(256) void weights_kernel(const float* __restrict__ comp,
                                                      const float* __restrict__ basis,
                                                      float* __restrict__ w,
                                                      int DIN, int DOUT) {
    int idx = blockIdx.x * blockDim.x + threadIdx.x;
    int total = R_ * DIN * DOUT;
    if (idx >= total) return;
    int o = idx % DOUT;
    int i = (idx / DOUT) % DIN;
    int r = idx / (DOUT * DIN);
    float acc = 0.f;
    #pragma unroll 6
    for (int b = 0; b < NBAS; ++b)
        acc += comp[r * NBAS + b] * basis[((size_t)b * DIN + i) * DOUT + o];
    w[idx] = acc;
}

// ---------------- scatter: agg[(dst*R+ety), j] += feat[src, c0+j] ----------------
template<int CHT>
__global__ __launch_bounds__(256) void scatter_kernel(const float* __restrict__ feat,
                                                      const int* __restrict__ src,
                                                      const int* __restrict__ dst,
                                                      const int* __restrict__ ety,
                                                      float* __restrict__ agg,
                                                      int E, int featDim, int c0) {
    long long t = (long long)blockIdx.x * blockDim.x + threadIdx.x;
    int e = (int)(t / CHT);
    int j = (int)(t % CHT);
    if (e >= E) return;
    int s   = src[e];
    int seg = dst[e] * R_ + ety[e];
    float v = feat[(size_t)s * featDim + c0 + j];
    atomicAdd(&agg[(size_t)seg * CHT + j], v);
}

// ---------------- contraction: h[n,o] (+)= sum_r (1/cnt) sum_k agg[n,r,k] w[r,c0+k,o]
//                  flags&1: initialize (add bias + x@root), else accumulate onto hout
//                  flags&2: relu at the end ----------------
template<int DOUT, int CHT>
__global__ __launch_bounds__(256) void contract_kernel(const float* __restrict__ agg,
                                                       const float* __restrict__ cnt,
                                                       const float* __restrict__ w, int c0, int DIN,
                                                       const float* __restrict__ xin,
                                                       const float* __restrict__ root,
                                                       const float* __restrict__ bias,
                                                       float* __restrict__ hout,
                                                       int N, int flags) {
    constexpr int OPT = DOUT / 4;      // threads per node (each does 4 outputs)
    constexpr int NPB = 256 / OPT;     // nodes per block
    int o4 = threadIdx.x % OPT;
    int nn = threadIdx.x / OPT;
    int n  = blockIdx.x * NPB + nn;
    if (n >= N) return;
    const int oo = o4 * 4;

    float ax = 0.f, ay = 0.f, az = 0.f, aw = 0.f;
    const float* arow = agg + (size_t)n * R_ * CHT;

    for (int r = 0; r < R_; ++r) {
        float s = 1.0f / fmaxf(cnt[n * R_ + r], 1.0f);
        const float4* a4 = (const float4*)(arow + r * CHT);
        const float* wr  = w + ((size_t)r * DIN + c0) * DOUT + oo;
        #pragma unroll 4
        for (int k4 = 0; k4 < CHT / 4; ++k4) {
            float4 a  = a4[k4];
            float4 b0 = *(const float4*)(wr + (k4 * 4 + 0) * DOUT);
            float4 b1 = *(const float4*)(wr + (k4 * 4 + 1) * DOUT);
            float4 b2 = *(const float4*)(wr + (k4 * 4 + 2) * DOUT);
            float4 b3 = *(const float4*)(wr + (k4 * 4 + 3) * DOUT);
            float f0 = a.x * s, f1 = a.y * s, f2 = a.z * s, f3 = a.w * s;
            ax += f0 * b0.x + f1 * b1.x + f2 * b2.x + f3 * b3.x;
            ay += f0 * b0.y + f1 * b1.y + f2 * b2.y + f3 * b3.y;
            az += f0 * b0.z + f1 * b1.z + f2 * b2.z + f3 * b3.z;
            aw += f0 * b0.w + f1 * b1.w + f2 * b2.w + f3 * b3.w;
        }
    }

    if (flags & 1) {
        // root term: h += x @ root, plus bias
        const float4* xr = (const float4*)(xin + (size_t)n * DIN);
        const float* rt  = root + oo;
        #pragma unroll 4
        for (int k4 = 0; k4 < DIN / 4; ++k4) {
            float4 a  = xr[k4];
            float4 b0 = *(const float4*)(rt + (k4 * 4 + 0) * DOUT);
            float4 b1 = *(const float4*)(rt + (k4 * 4 + 1) * DOUT);
            float4 b2 = *(const float4*)(rt + (k4 * 4 + 2) * DOUT);
            float4 b3 = *(const float4*)(rt + (k4 * 4 + 3) * DOUT);
            ax += a.x * b0.x + a.y * b1.x + a.z * b2.x + a.w * b3.x;
            ay += a.x * b0.y + a.y * b1.y + a.z * b2.y + a.w * b3.y;
            az += a.x * b0.z + a.y * b1.z + a.z * b2.z + a.w * b3.z;
            aw += a.x * b0.w + a.y * b1.w + a.z * b2.w + a.w * b3.w;
        }
        ax += bias[oo + 0]; ay += bias[oo + 1]; az += bias[oo + 2]; aw += bias[oo + 3];
    } else {
        float4 prev = *(const float4*)(hout + (size_t)n * DOUT + oo);
        ax += prev.x; ay += prev.y; az += prev.z; aw += prev.w;
    }

    if (flags & 2) {
        ax = fmaxf(ax, 0.f); ay = fmaxf(ay, 0.f);
        az = fmaxf(az, 0.f); aw = fmaxf(aw, 0.f);
    }
    float4 res = {ax, ay, az, aw};
    *(float4*)(hout + (size_t)n * DOUT + oo) = res;
}

// ---------------- classifier: out[n,a] = h[n,:] @ wc[:,a] + bc[a] ----------------
__global__ __launch_bounds__(256) void classifier_kernel(const float* __restrict__ h,
                                                         const float* __restrict__ wc,
                                                         const float* __restrict__ bc,
                                                         float* __restrict__ out, int N) {
    long long idx = (long long)blockIdx.x * blockDim.x + threadIdx.x;
    if (idx >= (long long)N * DADR) return;
    int n = (int)(idx / DADR);
    int a = (int)(idx % DADR);
    const float* hr = h + (size_t)n * DOUT2;
    float acc = bc[a];
    #pragma unroll 8
    for (int k = 0; k < DOUT2; ++k)
        acc += hr[k] * wc[(size_t)k * DADR + a];
    out[idx] = acc;
}

// ---------------- host-side pipeline (templated on chunk width) ----------------
template<int CHT>
static void run_pipeline(const float* x, const int* srcp, const int* dstp, const int* et,
                         const float* comp1, const float* basis1, const float* root1, const float* bias1,
                         const float* comp2, const float* basis2, const float* root2, const float* bias2,
                         const float* wc, const float* bc,
                         float* out, char* ws, int N, int E, hipStream_t stream) {
    float* cnt = (float*)ws;                         size_t off = (size_t)N * R_ * 4;
    float* agg = (float*)(ws + off);                 off += (size_t)N * R_ * CHT * 4;
    float* w1  = (float*)(ws + off);                 off += (size_t)R_ * DIN1 * DHID * 4;
    float* w2  = (float*)(ws + off);                 off += (size_t)R_ * DHID * DOUT2 * 4;
    float* h1  = (float*)(ws + off);                 off += (size_t)N * DHID * 4;
    float* h2  = (float*)(ws + off);

    size_t aggBytes = (size_t)N * R_ * CHT * 4;

    hipMemsetAsync(cnt, 0, (size_t)N * R_ * 4, stream);
    count_kernel<<<(E + 255) / 256, 256, 0, stream>>>(dstp, et, cnt, E);
    weights_kernel<<<(R_ * DIN1 * DHID + 255) / 256, 256, 0, stream>>>(comp1, basis1, w1, DIN1, DHID);
    weights_kernel<<<(R_ * DHID * DOUT2 + 255) / 256, 256, 0, stream>>>(comp2, basis2, w2, DHID, DOUT2);

    long long sthreads = (long long)E * CHT;
    int sgrid = (int)((sthreads + 255) / 256);

    // ---- layer 1: x(N,128) -> h1(N,128), relu ----
    constexpr int NC1 = DIN1 / CHT;
    for (int c = 0; c < NC1; ++c) {
        hipMemsetAsync(agg, 0, aggBytes, stream);
        scatter_kernel<CHT><<<sgrid, 256, 0, stream>>>(x, srcp, dstp, et, agg, E, DIN1, c * CHT);
        int flags = (c == 0 ? 1 : 0) | (c == NC1 - 1 ? 2 : 0);
        constexpr int NPB1 = 256 / (DHID / 4);
        contract_kernel<DHID, CHT><<<(N + NPB1 - 1) / NPB1, 256, 0, stream>>>(
            agg, cnt, w1, c * CHT, DIN1, x, root1, bias1, h1, N, flags);
    }

    // ---- layer 2: h1(N,128) -> h2(N,64), no relu ----
    constexpr int NC2 = DHID / CHT;
    for (int c = 0; c < NC2; ++c) {
        hipMemsetAsync(agg, 0, aggBytes, stream);
        scatter_kernel<CHT><<<sgrid, 256, 0, stream>>>(h1, srcp, dstp, et, agg, E, DHID, c * CHT);
        int flags = (c == 0 ? 1 : 0);
        constexpr int NPB2 = 256 / (DOUT2 / 4);
        contract_kernel<DOUT2, CHT><<<(N + NPB2 - 1) / NPB2, 256, 0, stream>>>(
            agg, cnt, w2, c * CHT, DHID, h1, root2, bias2, h2, N, flags);
    }

    // ---- classifier ----
    long long cthreads = (long long)N * DADR;
    classifier_kernel<<<(int)((cthreads + 255) / 256), 256, 0, stream>>>(h2, wc, bc, out, N);
}

static size_t ws_needed(int N, int CHT) {
    return ((size_t)N * R_                      // cnt
          + (size_t)N * R_ * CHT                // agg
          + (size_t)R_ * DIN1 * DHID            // w1
          + (size_t)R_ * DHID * DOUT2           // w2
          + (size_t)N * DHID                    // h1
          + (size_t)N * DOUT2) * 4;             // h2
}

extern "C" void kernel_launch(void* const* d_in, const int* in_sizes, int n_in,
                              void* d_out, int out_size, void* d_ws, size_t ws_size,
                              hipStream_t stream) {
    const float* x      = (const float*)d_in[0];
    const int*   ei     = (const int*)d_in[1];
    const int*   et     = (const int*)d_in[2];
    const float* comp1  = (const float*)d_in[3];
    const float* basis1 = (const float*)d_in[4];
    const float* root1  = (const float*)d_in[5];
    const float* bias1  = (const float*)d_in[6];
    const float* comp2  = (const float*)d_in[7];
    const float* basis2 = (const float*)d_in[8];
    const float* root2  = (const float*)d_in[9];
    const float* bias2  = (const float*)d_in[10];
    const float* wc     = (const float*)d_in[11];
    const float* bc     = (const float*)d_in[12];
    float* out = (float*)d_out;

    int E = in_sizes[1] / 2;
    int N = in_sizes[0] / DIN1;
    const int* srcp = ei;
    const int* dstp = ei + E;
    char* ws = (char*)d_ws;

    if (ws_size >= ws_needed(N, 64)) {
        run_pipeline<64>(x, srcp, dstp, et, comp1, basis1, root1, bias1,
                         comp2, basis2, root2, bias2, wc, bc, out, ws, N, E, stream);
    } else if (ws_size >= ws_needed(N, 32)) {
        run_pipeline<32>(x, srcp, dstp, et, comp1, basis1, root1, bias1,
                         comp2, basis2, root2, bias2, wc, bc, out, ws, N, E, stream);
    } else {
        run_pipeline<16>(x, srcp, dstp, et, comp1, basis1, root1, bias1,
                         comp2, basis2, root2, bias2, wc, bc, out, ws, N, E, stream);
    }
}